// Round 15
// baseline (2071.944 us; speedup 1.0000x reference)
//
#include <hip/hip_runtime.h>
#include <hip/hip_bf16.h>

#define DINL __device__ __forceinline__

namespace {

typedef unsigned long long u64;

constexpr int Tn = 256;   // sequence length
constexpr int Bn = 64;    // batch
constexpr int HDn = 256;  // per-direction hidden
constexpr int Kt = 20;    // tagset
constexpr int STOPt = 19;
constexpr int STARTt = 18;
constexpr float NEGV = -10000.0f;

DINL float sigm(float x) { return 1.0f / (1.0f + __expf(-x)); }
DINL float tanh_f(float x) {
  float ax = fabsf(x);
  float e = __expf(-2.0f * ax);       // in (0,1]
  float t = (1.0f - e) / (1.0f + e);
  return x < 0.0f ? -t : t;
}

// ---------------- K0: bump per-launch epoch (replay disambiguation) ----------
__global__ void k_epoch(unsigned* ep) {
  if (threadIdx.x == 0)
    __hip_atomic_fetch_add(ep, 1u, __ATOMIC_RELAXED, __HIP_MEMORY_SCOPE_AGENT);
}

// ---------------- K1: FUSED persistent bidirectional LSTM --------------------
// 256 blocks x 128 thr. Handshake protocol = round 10 EXACTLY (proven 1150us).
// In-kernel input projection (no k_wt/k_xproj dispatches, no xproj buffer):
//   - W_ih slice (32 gate-rows x 300) -> LDS once (41.5KB)
//   - embs DOUBLE-BUFFERED in LDS (2 x 20KB): xp(st) reads embs[st&1] while
//     the stage step writes embs[(st&1)^1] for st+1; B3 orders write->read.
//   - xp partials accumulate into the SAME acc[b][g] as the W_hh GEMV; the
//     kc-butterfly reduces both sums together. Bias added at update.
//   - xp compute sits BEFORE the flag poll (h-independent) -> hides under
//     producer publish latency, and no registers are in flight across it.
// r14 lesson (recorded): never split an inline-asm load from its s_waitcnt
// across register-heavy code — the allocator may spill/copy the in-flight
// destination registers before the wait (silent corruption). The h-load is
// back to the COMBINED load+wait asm block (r10-proven).
__global__ __launch_bounds__(128) void k_lstm(
    const float* __restrict__ whh_f, const float* __restrict__ whh_b,
    const float* __restrict__ wih_f, const float* __restrict__ wih_b,
    const float* __restrict__ b_f, const float* __restrict__ b_b,
    const int* __restrict__ sentence, const float* __restrict__ table,
    float* __restrict__ h_all, int* __restrict__ flags,
    int* __restrict__ xcdtab, const unsigned* __restrict__ ep) {
  __shared__ __align__(16) float hl[16 * 256];       // h tile        (16 KB)
  __shared__ __align__(16) float embs[2][16 * 320];  // emb dbuf    (2x20 KB)
  __shared__ __align__(16) float wihs[32 * 324];     // W_ih slice (41.5 KB)
  __shared__ int fastsh;

  int tid = threadIdx.x;
  int bid = blockIdx.x;
  int gid = bid & 7;        // dir = gid>>2, bg = gid&3 (XCD-affine grouping)
  int s = bid >> 3;         // slice 0..31 (8 hidden cols each)
  int dir = gid >> 2;
  int bg = gid & 3;
  const float* whh = dir ? whh_b : whh_f;
  const float* wih = dir ? wih_b : wih_f;

  int c = tid >> 4;         // hidden-col within slice, 0..7
  int kc = tid & 15;        // k-partition (16 interleaved granules of 4)

  // --- per-launch epoch + XCD consensus (r10-proven) -------------------------
  unsigned E =
      __hip_atomic_load(ep, __ATOMIC_RELAXED, __HIP_MEMORY_SCOPE_AGENT);
  unsigned xcd = __builtin_amdgcn_s_getreg((3 << 11) | (0 << 6) | 20) & 0xFu;
  if (tid == 0) {
    __hip_atomic_store(&xcdtab[(gid << 5) + s], (int)((E << 4) | xcd),
                       __ATOMIC_RELAXED, __HIP_MEMORY_SCOPE_AGENT);
  }
  if (tid < 64) {
    const int* xp_ = xcdtab + (gid << 5) + (tid & 31);
    unsigned v;
    for (;;) {
      v = (unsigned)__hip_atomic_load(xp_, __ATOMIC_RELAXED,
                                      __HIP_MEMORY_SCOPE_AGENT);
      bool rdy = (v >> 4) == (E & 0x0FFFFFFFu);
      if (__all((tid < 32) ? rdy : 1)) break;
      __builtin_amdgcn_s_sleep(1);
    }
    int mine = (int)(v & 0xFu);
    int ref = __shfl(mine, 0, 64);
    bool eq = (mine == ref);
    bool alleq = __all((tid < 32) ? eq : 1);
    if (tid == 0) fastsh = alleq ? 1 : 0;
  }

  // --- W_ih slice -> LDS (one-time). local row r = g*8+cc <-> global
  // row g*256 + s*8 + cc. Row stride 324 f; cols >= 300 zero-padded.
  for (int i = tid; i < 32 * 81; i += 128) {
    int r = i / 81, gi = i - r * 81;
    int g = r >> 3, cc = r & 7;
    float4 v = {0.0f, 0.0f, 0.0f, 0.0f};
    if (gi < 75)
      v = *(const float4*)(wih + ((size_t)(g * 256 + s * 8 + cc)) * 300 +
                           4 * gi);
    *(float4*)&wihs[r * 324 + 4 * gi] = v;
  }

  // --- W_hh into registers: w4[g][jj] = W_hh[g*256+s*8+c][(kc+16jj)*4 ..+4)
  float4 w4[4][4];
#pragma unroll
  for (int g = 0; g < 4; ++g) {
    const float* src = whh + ((size_t)(g * 256 + s * 8 + c)) * 256;
#pragma unroll
    for (int jj = 0; jj < 4; ++jj)
      w4[g][jj] = *(const float4*)(src + ((kc + (jj << 4)) << 2));
  }

  // --- bias for this thread's 4 gates (col s*8+c)
  float bias4[4];
  {
    const float* bsrc = dir ? b_b : b_f;
#pragma unroll
    for (int g = 0; g < 4; ++g) bias4[g] = bsrc[g * 256 + s * 8 + c];
  }

  // --- prologue: stage embs[0] for st=0 (token read straight from sentence)
  {
    int xt0 = dir ? (Tn - 1) : 0;
    int row = tid >> 3, j8 = tid & 7;
    int tk = sentence[(bg * 16 + row) * Tn + xt0];
#pragma unroll
    for (int jj = 0; jj < 10; ++jj) {
      int gi = j8 + 8 * jj;
      float4 v = {0.0f, 0.0f, 0.0f, 0.0f};
      if (gi < 75) v = *(const float4*)(table + (size_t)tk * 300 + 4 * gi);
      *(float4*)&embs[0][row * 320 + 4 * gi] = v;
    }
  }
  __syncthreads();   // wihs + embs[0] ready; fastsh visible
  const bool fast = (fastsh != 0);
  const unsigned base = E * 256u;

  float c_reg = 0.0f;

  for (int st = 0; st < Tn; ++st) {
    int xt = dir ? (Tn - 1 - st) : st;
    int eb = st & 1;
    const float* emb = embs[eb];

    float acc[16][4];
#pragma unroll
    for (int b = 0; b < 16; ++b)
#pragma unroll
      for (int g = 0; g < 4; ++g) acc[b][g] = 0.0f;

    // 1. xp partials (h-independent, BEFORE the poll): acc += emb . W_ih
#pragma unroll
    for (int jj = 0; jj < 5; ++jj) {
      int gq = (kc + (jj << 4)) << 2;   // float index of granule
      float4 wv0 = *(const float4*)&wihs[(0 * 8 + c) * 324 + gq];
      float4 wv1 = *(const float4*)&wihs[(1 * 8 + c) * 324 + gq];
      float4 wv2 = *(const float4*)&wihs[(2 * 8 + c) * 324 + gq];
      float4 wv3 = *(const float4*)&wihs[(3 * 8 + c) * 324 + gq];
#pragma unroll
      for (int b = 0; b < 16; ++b) {
        float4 ev = *(const float4*)&emb[b * 320 + gq];
        acc[b][0] += wv0.x * ev.x + wv0.y * ev.y + wv0.z * ev.z + wv0.w * ev.w;
        acc[b][1] += wv1.x * ev.x + wv1.y * ev.y + wv1.z * ev.z + wv1.w * ev.w;
        acc[b][2] += wv2.x * ev.x + wv2.y * ev.y + wv2.z * ev.z + wv2.w * ev.w;
        acc[b][3] += wv3.x * ev.x + wv3.y * ev.y + wv3.z * ev.z + wv3.w * ev.w;
      }
    }

    if (st > 0) {
      // 2. flag poll (r10): wave0 lanes watch the 32 slice-flags
      if (tid < 64) {
        const int* fp = flags + ((gid << 5) + (tid & 31)) * 4;
        if (fast) {
          for (;;) {   // pure spin: catch = load latency
            unsigned v = (unsigned)__hip_atomic_load(
                fp, __ATOMIC_RELAXED, __HIP_MEMORY_SCOPE_AGENT);
            int d = (int)(v - base);
            if (__all((tid < 32) ? (d >= st) : 1)) break;
          }
        } else {
          for (;;) {
            unsigned v = (unsigned)__hip_atomic_load(
                fp, __ATOMIC_RELAXED, __HIP_MEMORY_SCOPE_AGENT);
            int d = (int)(v - base);
            if (__all((tid < 32) ? (d >= st) : 1)) break;
            __builtin_amdgcn_s_sleep(1);
          }
        }
      }
      __syncthreads();  // B1: flags seen; prev-step hl readers done

      // 3. COMBINED batched h read: loads + waitcnt in ONE asm block
      int pt = dir ? (xt + 1) : (xt - 1);
      const float* hsrc =
          h_all + ((size_t)(dir * Tn + pt) * 64 + bg * 16) * 256;
      const char* tb = (const char*)hsrc + (size_t)tid * 16;
      const char* p0 = tb;
      const char* p1 = tb + 4096;
      const char* p2 = tb + 8192;
      const char* p3 = tb + 12288;
      float4 q0, q1, q2, q3, q4, q5, q6, q7;
      asm volatile(
          "global_load_dwordx4 %0, %8, off sc1\n\t"
          "global_load_dwordx4 %1, %8, off offset:2048 sc1\n\t"
          "global_load_dwordx4 %2, %9, off sc1\n\t"
          "global_load_dwordx4 %3, %9, off offset:2048 sc1\n\t"
          "global_load_dwordx4 %4, %10, off sc1\n\t"
          "global_load_dwordx4 %5, %10, off offset:2048 sc1\n\t"
          "global_load_dwordx4 %6, %11, off sc1\n\t"
          "global_load_dwordx4 %7, %11, off offset:2048 sc1\n\t"
          "s_waitcnt vmcnt(0)"
          : "=&v"(q0), "=&v"(q1), "=&v"(q2), "=&v"(q3), "=&v"(q4), "=&v"(q5),
            "=&v"(q6), "=&v"(q7)
          : "v"(p0), "v"(p1), "v"(p2), "v"(p3));
      *(float4*)&hl[(tid + 0 * 128) << 2] = q0;
      *(float4*)&hl[(tid + 1 * 128) << 2] = q1;
      *(float4*)&hl[(tid + 2 * 128) << 2] = q2;
      *(float4*)&hl[(tid + 3 * 128) << 2] = q3;
      *(float4*)&hl[(tid + 4 * 128) << 2] = q4;
      *(float4*)&hl[(tid + 5 * 128) << 2] = q5;
      *(float4*)&hl[(tid + 6 * 128) << 2] = q6;
      *(float4*)&hl[(tid + 7 * 128) << 2] = q7;
      __syncthreads();  // B2: hl ready

      // 4. GEMV: each b128 read feeds 16 FMAs (4 gates x 4 k)
#pragma unroll
      for (int b = 0; b < 16; ++b) {
#pragma unroll
        for (int jj = 0; jj < 4; ++jj) {
          float4 hv = *(const float4*)&hl[b * 256 + ((kc + (jj << 4)) << 2)];
#pragma unroll
          for (int g = 0; g < 4; ++g) {
            acc[b][g] += w4[g][jj].x * hv.x + w4[g][jj].y * hv.y +
                         w4[g][jj].z * hv.z + w4[g][jj].w * hv.w;
          }
        }
      }
    }

    // 5. butterfly over kc; final acc[0][g] = full gates of batch b=kc
#pragma unroll
    for (int r = 0; r < 4; ++r) {
      int m = 1 << r;
      int kb = (kc >> r) & 1;
#pragma unroll
      for (int ii = 0; ii < (16 >> (r + 1)); ++ii) {
#pragma unroll
        for (int g = 0; g < 4; ++g) {
          float e = acc[2 * ii][g], o = acc[2 * ii + 1][g];
          float kept = kb ? o : e;
          float sent = kb ? e : o;
          acc[ii][g] = kept + __shfl_xor(sent, m, 64);
        }
      }
    }

    // 6. update (b = kc, col = s*8+c); gate order i,f,g,o; bias here
    {
      float gi = acc[0][0] + bias4[0];
      float gf = acc[0][1] + bias4[1];
      float gg = acc[0][2] + bias4[2];
      float go = acc[0][3] + bias4[3];
      c_reg = sigm(gf) * c_reg + sigm(gi) * tanh_f(gg);
      float h = sigm(go) * tanh_f(c_reg);
      size_t hi = ((size_t)(dir * Tn + xt) * 64 + bg * 16 + kc) * 256 + s * 8 +
                  c;
      if (fast) {
        h_all[hi] = h;   // plain: dirty in the group's (shared) L2
      } else {
        __hip_atomic_store(&h_all[hi], h, __ATOMIC_RELAXED,
                           __HIP_MEMORY_SCOPE_AGENT);
      }
    }

    // 7. stage embs[eb^1] for st+1 (token direct from sentence); the B3
    //    barrier below orders these writes before next iteration's xp reads.
    if (st + 1 < Tn) {
      int xtn = dir ? (Tn - 2 - st) : (st + 1);
      int row = tid >> 3, j8 = tid & 7;
      int tk = sentence[(bg * 16 + row) * Tn + xtn];
      float* ed = embs[eb ^ 1];
#pragma unroll
      for (int jj = 0; jj < 10; ++jj) {
        int gi = j8 + 8 * jj;
        float4 v = {0.0f, 0.0f, 0.0f, 0.0f};
        if (gi < 75) v = *(const float4*)(table + (size_t)tk * 300 + 4 * gi);
        *(float4*)&ed[row * 320 + 4 * gi] = v;
      }
    }

    // 8. drain h stores, publish flag
    asm volatile("s_waitcnt vmcnt(0)" ::: "memory");
    __syncthreads();  // B3: h drained; embs[eb^1] writes ordered
    if (tid == 0) {
      int fv = (int)(base + (unsigned)(st + 1));
      if (fast) {
        flags[((gid << 5) + s) * 4] = fv;
      } else {
        __hip_atomic_store(flags + ((gid << 5) + s) * 4, fv, __ATOMIC_RELAXED,
                           __HIP_MEMORY_SCOPE_AGENT);
      }
    }
  }
}

// ---------------- K4: feats = concat(hf,hb) @ W_out^T + b_out ----------------
__global__ __launch_bounds__(256) void k_feats(const float* __restrict__ h_all,
                                               const float* __restrict__ Wout,
                                               const float* __restrict__ bout,
                                               float* __restrict__ feats) {
  __shared__ float Wl[20 * 512];   // 40KB
  __shared__ float hlf[64 * 256];  // 64KB, XOR-swizzled

  int tid = threadIdx.x;
  int t = blockIdx.x;
  for (int i = tid; i < 20 * 512; i += 256) Wl[i] = Wout[i];

  float acc[5] = {0, 0, 0, 0, 0};
  int b = tid & 63, kg5 = tid >> 6;
  int swz = b & 7;

  for (int d = 0; d < 2; ++d) {
    __syncthreads();
    const float* hsrc = h_all + ((size_t)(d * Tn + t)) * 64 * 256;
#pragma unroll 8
    for (int i = 0; i < 64; ++i) {
      int idx = i * 256 + tid;
      int hb = idx >> 8, k = idx & 255;
      hlf[hb * 256 + 4 * ((k >> 2) ^ (hb & 7)) + (k & 3)] = hsrc[idx];
    }
    __syncthreads();
    for (int jg = 0; jg < 64; ++jg) {
      float4 hv = *(const float4*)&hlf[b * 256 + 4 * (jg ^ swz)];
#pragma unroll
      for (int kk = 0; kk < 5; ++kk) {
        int krow = kg5 * 5 + kk;
        float4 wvv = *(const float4*)&Wl[krow * 512 + d * 256 + jg * 4];
        acc[kk] += hv.x * wvv.x + hv.y * wvv.y + hv.z * wvv.z + hv.w * wvv.w;
      }
    }
  }
#pragma unroll
  for (int kk = 0; kk < 5; ++kk) {
    int krow = kg5 * 5 + kk;
    feats[((size_t)b * Tn + t) * Kt + krow] = acc[kk] + bout[krow];
  }
}

// ---------------- K5: Viterbi decode, one wave per batch element -------------
__global__ __launch_bounds__(64) void k_viterbi(const float* __restrict__ feats,
                                                const float* __restrict__ trans,
                                                const int* __restrict__ length,
                                                float* __restrict__ out) {
  __shared__ float tr[400];
  __shared__ float fv[20];
  __shared__ float term[20];
  __shared__ unsigned char bps[256][20];

  int b = blockIdx.x;
  int lane = threadIdx.x;
  for (int i = lane; i < 400; i += 64) tr[i] = trans[i];
  if (lane < 20) fv[lane] = (lane == STARTt) ? 0.0f : NEGV;
  int len = length[b];
  __syncthreads();

  for (int t = 0; t < Tn; ++t) {
    float nf = 0.0f;
    int bp = 0;
    if (lane < 20) {
      if (t < len) {
        float vmax = -3.4e38f;
        int pb = 0;
#pragma unroll
        for (int p = 0; p < 20; ++p) {
          float v = fv[p] + tr[lane * 20 + p];
          if (v > vmax) { vmax = v; pb = p; }   // strict > == first-argmax
        }
        nf = vmax + feats[((size_t)b * Tn + t) * Kt + lane];
        bp = pb;
      } else {
        nf = fv[lane];
        bp = lane;
      }
    }
    __syncthreads();
    if (lane < 20) {
      fv[lane] = nf;
      bps[t][lane] = (unsigned char)bp;
    }
    __syncthreads();
  }

  if (lane < 20) term[lane] = fv[lane] + tr[STOPt * 20 + lane];
  __syncthreads();
  if (lane == 0) {
    float smax = term[0];
    int last = 0;
    for (int p = 1; p < 20; ++p)
      if (term[p] > smax) { smax = term[p]; last = p; }
    out[b] = smax;                     // viterbi score
    int tag = last;
    for (int t = Tn - 1; t >= 0; --t) {
      out[64 + b * Tn + t] = (float)tag;
      tag = bps[t][tag];
    }
  }
}

}  // namespace

extern "C" void kernel_launch(void* const* d_in, const int* in_sizes, int n_in,
                              void* d_out, int out_size, void* d_ws,
                              size_t ws_size, hipStream_t stream) {
  const int* sentence = (const int*)d_in[0];
  const int* length = (const int*)d_in[1];
  const float* table = (const float*)d_in[2];
  const float* w_ih_f = (const float*)d_in[3];
  const float* w_hh_f = (const float*)d_in[4];
  const float* b_f = (const float*)d_in[5];
  const float* w_ih_b = (const float*)d_in[6];
  const float* w_hh_b = (const float*)d_in[7];
  const float* b_b = (const float*)d_in[8];
  const float* W_out = (const float*)d_in[9];
  const float* b_out = (const float*)d_in[10];
  const float* trans = (const float*)d_in[11];
  float* out = (float*)d_out;

  // workspace layout (floats)
  float* ws = (float*)d_ws;
  float* h_all = ws;                                  // 8,388,608 f (33.5 MB)
  float* feats = h_all + (size_t)8388608;             // 327,680 f
  int* flags = (int*)(feats + (size_t)Bn * Tn * Kt);  // 1024 ints (16B-strided)
  int* xcdtab = flags + 1024;                         // 256 ints
  unsigned* ep = (unsigned*)(xcdtab + 256);           // 1 int epoch
  (void)ws_size; (void)in_sizes; (void)n_in; (void)out_size;

  k_epoch<<<dim3(1), dim3(64), 0, stream>>>(ep);
  k_lstm<<<dim3(256), dim3(128), 0, stream>>>(w_hh_f, w_hh_b, w_ih_f, w_ih_b,
                                              b_f, b_b, sentence, table, h_all,
                                              flags, xcdtab, ep);
  k_feats<<<dim3(256), dim3(256), 0, stream>>>(h_all, W_out, b_out, feats);
  k_viterbi<<<dim3(64), dim3(64), 0, stream>>>(feats, trans, length, out);
}